// Round 1
// baseline (2728.808 us; speedup 1.0000x reference)
//
#include <hip/hip_runtime.h>

// Problem constants (match reference)
#define BATCH 8
#define NPTS  32768
#define DIM   256
#define NSAMP 64      // NPOINT (fps samples)
#define NNBR  8       // ball-query neighbors
#define LN_EPS 1e-5f

// FPS decomposition: 32 blocks per batch, 256 threads, 4 points/thread,
// coords held in registers, per-batch device-scope barrier per iteration.
#define FPS_BPB 32                 // blocks per batch
#define FPS_TPB 256                // threads per block
#define FPS_PPT 4                  // (NPTS/FPS_BPB)/FPS_TPB points per thread

// Inter-kernel buffers as device globals (no d_ws dependence).
__device__ float g_sample_coor[BATCH * NSAMP * 3];
__device__ float g_diff_coor[BATCH * NSAMP * 3];
__device__ float g_qbuf[BATCH * NSAMP * DIM];
__device__ float g_kbuf[BATCH * NSAMP * DIM];
__device__ int   g_fidx[BATCH * NSAMP];

// FPS cross-block state. Partials double-buffered by iteration parity so a
// single barrier per iteration is race-free (a block can only write slot p
// at iter s+2 after every block has read slot p at iter s — the barrier at
// s+1 orders it). Zero-initialized at module load; barrier counter returns
// to 0 after every round, generation is monotonically increasing (relative
// compares only), so repeated launches / graph replays are safe.
__device__ double   g_part_v[2][BATCH][FPS_BPB];
__device__ int      g_part_i[2][BATCH][FPS_BPB];
__device__ unsigned g_bar_cnt[BATCH];
__device__ unsigned g_bar_gen[BATCH];

// I/O dtypes (forensically established):
//  - inputs  = FLOAT32 storage (R2: reading as bf16 created sNaN patterns -> NaN)
//  - outputs = FLOAT32 storage (R3-R5: bf16 ushort writes gave deterministic
//    6.72 error == interleaved-bf16-read-as-f32 signature; index logic proven
//    robust under f32-asm/f32-compiler/f64 arithmetic)

// Index-critical distances in f64: exact for f32 inputs (diff exact, square
// 48<53 bits), contraction-immune, and matches any reasonable np ref rounding.
__device__ __forceinline__ double dist2_64(float px, float py, float pz,
                                           float cx, float cy, float cz) {
    double dx = (double)px - (double)cx;
    double dy = (double)py - (double)cy;
    double dz = (double)pz - (double)cz;
    return (dx * dx + dy * dy) + dz * dz;   // numpy's (x^2+y^2)+z^2 order
}

// Per-batch sense-reversing barrier across FPS_BPB blocks.
// Device-scope (AGENT) atomics: per-XCD L2s are not coherent, so both the
// counter/generation traffic and the partial payloads use agent-scope ops.
__device__ __forceinline__ void batch_barrier(int b) {
    __syncthreads();
    if (threadIdx.x == 0) {
        __threadfence();   // make this block's partial stores visible pre-arrival
        unsigned gen = __hip_atomic_load(&g_bar_gen[b], __ATOMIC_RELAXED,
                                         __HIP_MEMORY_SCOPE_AGENT);
        unsigned arr = __hip_atomic_fetch_add(&g_bar_cnt[b], 1u, __ATOMIC_ACQ_REL,
                                              __HIP_MEMORY_SCOPE_AGENT);
        if (arr == FPS_BPB - 1) {
            __hip_atomic_store(&g_bar_cnt[b], 0u, __ATOMIC_RELAXED,
                               __HIP_MEMORY_SCOPE_AGENT);
            __hip_atomic_fetch_add(&g_bar_gen[b], 1u, __ATOMIC_RELEASE,
                                   __HIP_MEMORY_SCOPE_AGENT);
        } else {
            while (__hip_atomic_load(&g_bar_gen[b], __ATOMIC_ACQUIRE,
                                     __HIP_MEMORY_SCOPE_AGENT) == gen)
                __builtin_amdgcn_s_sleep(2);
        }
        __threadfence();
    }
    __syncthreads();
}

// ============================================================================
// Kernel A: farthest-point sampling, multi-block per batch.
// Grid = BATCH*FPS_BPB blocks x 256 threads. Each thread owns 4 points whose
// coords live in registers (loaded once) + 4 running f64 min-distances.
// Per iteration: register update -> wave/block argmax -> per-batch barrier ->
// every block redundantly reduces the 32 block partials (lowest-index
// tie-break, identical semantics to the verified single-block version).
// ============================================================================
__global__ __launch_bounds__(FPS_TPB) void fps_kernel(
    const float* __restrict__ coor)
{
    const int blk = blockIdx.x & (FPS_BPB - 1);
    const int b   = blockIdx.x >> 5;          // FPS_BPB == 32
    const int t   = threadIdx.x;
    const float* cb = coor + (size_t)b * NPTS * 3;
    const int base = blk << 10;               // blk * (NPTS/FPS_BPB) = blk*1024

    float  px[FPS_PPT], py[FPS_PPT], pz[FPS_PPT];
    double dist[FPS_PPT];
#pragma unroll
    for (int k = 0; k < FPS_PPT; ++k) {
        const int p = base + (k << 8) + t;    // lane-contiguous per k
        px[k] = cb[p * 3 + 0];
        py[k] = cb[p * 3 + 1];
        pz[k] = cb[p * 3 + 2];
        dist[k] = 1e10;
    }

    __shared__ double s_rv[FPS_TPB / 64];
    __shared__ int    s_ri[FPS_TPB / 64];
    __shared__ float  s_ctr[3];

    // sample 0 = point 0 (pointnet2 semantics)
    float cx = cb[0], cy = cb[1], cz = cb[2];
    if (blk == 0 && t == 0) {
        g_fidx[b * NSAMP + 0] = 0;
        g_sample_coor[(b * NSAMP + 0) * 3 + 0] = cx;
        g_sample_coor[(b * NSAMP + 0) * 3 + 1] = cy;
        g_sample_coor[(b * NSAMP + 0) * 3 + 2] = cz;
    }

    for (int s = 1; s < NSAMP; ++s) {
        // ---- register distance update + thread-local argmax ----
        double best = -1.0; int bidx = 0x7fffffff;
#pragma unroll
        for (int k = 0; k < FPS_PPT; ++k) {
            const int p = base + (k << 8) + t;
            double d2 = dist2_64(px[k], py[k], pz[k], cx, cy, cz);
            double nd = fmin(dist[k], d2);
            dist[k] = nd;
            if (nd > best) { best = nd; bidx = p; }  // strict > keeps lowest p
        }
        // ---- wave butterfly argmax, lowest-index tie-break ----
#pragma unroll
        for (int off = 32; off > 0; off >>= 1) {
            double ov = __shfl_xor(best, off);
            int    oi = __shfl_xor(bidx, off);
            if (ov > best || (ov == best && oi < bidx)) { best = ov; bidx = oi; }
        }
        if ((t & 63) == 0) { s_rv[t >> 6] = best; s_ri[t >> 6] = bidx; }
        __syncthreads();

        const int par = s & 1;
        if (t == 0) {
            double bv = s_rv[0]; int bi = s_ri[0];
#pragma unroll
            for (int w = 1; w < FPS_TPB / 64; ++w) {
                double v = s_rv[w]; int i = s_ri[w];
                if (v > bv || (v == bv && i < bi)) { bv = v; bi = i; }
            }
            __hip_atomic_store(&g_part_v[par][b][blk], bv, __ATOMIC_RELAXED,
                               __HIP_MEMORY_SCOPE_AGENT);
            __hip_atomic_store(&g_part_i[par][b][blk], bi, __ATOMIC_RELAXED,
                               __HIP_MEMORY_SCOPE_AGENT);
        }

        batch_barrier(b);

        // ---- every block redundantly reduces the 32 partials (wave 0) ----
        if (t < 64) {
            double bv; int bi;
            if (t < FPS_BPB) {
                bv = __hip_atomic_load(&g_part_v[par][b][t], __ATOMIC_RELAXED,
                                       __HIP_MEMORY_SCOPE_AGENT);
                bi = __hip_atomic_load(&g_part_i[par][b][t], __ATOMIC_RELAXED,
                                       __HIP_MEMORY_SCOPE_AGENT);
            } else {
                bv = -2.0; bi = 0x7fffffff;   // real dists >= 0: never wins
            }
#pragma unroll
            for (int off = 32; off > 0; off >>= 1) {
                double ov = __shfl_xor(bv, off);
                int    oi = __shfl_xor(bi, off);
                if (ov > bv || (ov == bv && oi < bi)) { bv = ov; bi = oi; }
            }
            if (t == 0) {
                float wx = cb[bi * 3 + 0];
                float wy = cb[bi * 3 + 1];
                float wz = cb[bi * 3 + 2];
                s_ctr[0] = wx; s_ctr[1] = wy; s_ctr[2] = wz;
                if (blk == 0) {
                    g_fidx[b * NSAMP + s] = bi;
                    g_sample_coor[(b * NSAMP + s) * 3 + 0] = wx;
                    g_sample_coor[(b * NSAMP + s) * 3 + 1] = wy;
                    g_sample_coor[(b * NSAMP + s) * 3 + 2] = wz;
                }
            }
        }
        __syncthreads();
        cx = s_ctr[0]; cy = s_ctr[1]; cz = s_ctr[2];
    }
}

// ============================================================================
// Kernel B: ball query (first-8 within radius by index order, f64 distance,
// early exit) + grouped-feature max (out0 = global_x, f32) + diff_coor mean.
// One wave per (b,s) center.
// ============================================================================
__global__ __launch_bounds__(64) void ballquery_kernel(
    const float* __restrict__ coor,
    const float* __restrict__ x,
    float* __restrict__ out0)
{
    const int bid = blockIdx.x;
    const int b = bid >> 6, s = bid & 63;
    const int lane = threadIdx.x;
    const float* cb = coor + (size_t)b * NPTS * 3;

    const float cx = g_sample_coor[(b * NSAMP + s) * 3 + 0];
    const float cy = g_sample_coor[(b * NSAMP + s) * 3 + 1];
    const float cz = g_sample_coor[(b * NSAMP + s) * 3 + 2];

    __shared__ int s_nidx[NNBR];
    int found = 0;
    for (int ch = 0; ch < NPTS / 64 && found < NNBR; ++ch) {
        int p = (ch << 6) + lane;
        double d2 = dist2_64(cb[p * 3 + 0], cb[p * 3 + 1], cb[p * 3 + 2],
                             cx, cy, cz);
        unsigned long long m = __ballot(d2 < 16.0);   // strict <
        while (m && found < NNBR) {                   // wave-uniform
            int bpos = __ffsll(m) - 1;
            if (lane == 0) s_nidx[found] = (ch << 6) + bpos;
            ++found;
            m &= m - 1;
        }
    }
    if (lane == 0) {                         // pad with first hit (or 0 if none)
        if (found == 0) { s_nidx[0] = 0; found = 1; }
        int f0 = s_nidx[0];
        for (int j = found; j < NNBR; ++j) s_nidx[j] = f0;
    }
    __syncthreads();

    // grouped-feature max -> out0 (4 channels/lane; f32 in, f32 out)
    int c0 = lane * 4;
    float a0 = -1e30f, a1 = -1e30f, a2 = -1e30f, a3 = -1e30f;
#pragma unroll
    for (int j = 0; j < NNBR; ++j) {
        const float4 v = *(const float4*)(x + ((size_t)b * NPTS + s_nidx[j]) * DIM + c0);
        a0 = fmaxf(a0, v.x); a1 = fmaxf(a1, v.y);
        a2 = fmaxf(a2, v.z); a3 = fmaxf(a3, v.w);
    }
    float4 o; o.x = a0; o.y = a1; o.z = a2; o.w = a3;
    *(float4*)(out0 + ((size_t)(b * NSAMP + s)) * DIM + c0) = o;

    // diff_coor = mean_j (p_j - c)   (continuous path)
    if (lane < 3) {
        float sum = 0.f;
#pragma unroll
        for (int j = 0; j < NNBR; ++j) {
            float pv = cb[s_nidx[j] * 3 + lane];
            sum += pv - ((lane == 0) ? cx : (lane == 1) ? cy : cz);
        }
        g_diff_coor[(b * NSAMP + s) * 3 + lane] = sum * 0.125f;
    }
}

// ============================================================================
// Kernel C1: LayerNorm + row @ W^T. One block per (b, s, which) row.
// which==0: q from diff_x = global_x(out0) - sample_x ; which==1: k from sample_x.
// ============================================================================
__global__ __launch_bounds__(256) void ln_gemm_kernel(
    const float* __restrict__ x,
    const float* __restrict__ out0,
    const float* __restrict__ Wq,
    const float* __restrict__ Wk,
    const float* __restrict__ gq, const float* __restrict__ bq,
    const float* __restrict__ gk, const float* __restrict__ bk)
{
    const int bid = blockIdx.x;
    const int which = bid & 1;
    const int s = (bid >> 1) & 63;
    const int b = bid >> 7;
    const int c = threadIdx.x;

    const int fidx = g_fidx[b * NSAMP + s];
    float xs = x[((size_t)b * NPTS + fidx) * DIM + c];
    float r  = which ? xs : (out0[(size_t)(b * NSAMP + s) * DIM + c] - xs);

    __shared__ float red[4];
    __shared__ float ln[DIM];

    float sum = r;
#pragma unroll
    for (int off = 32; off; off >>= 1) sum += __shfl_xor(sum, off);
    int wid = c >> 6;
    if ((c & 63) == 0) red[wid] = sum;
    __syncthreads();
    float mean = (red[0] + red[1] + red[2] + red[3]) * (1.0f / DIM);
    float d = r - mean;
    float vs = d * d;
#pragma unroll
    for (int off = 32; off; off >>= 1) vs += __shfl_xor(vs, off);
    __syncthreads();
    if ((c & 63) == 0) red[wid] = vs;
    __syncthreads();
    float var = (red[0] + red[1] + red[2] + red[3]) * (1.0f / DIM);
    float rs = 1.0f / sqrtf(var + LN_EPS);

    ln[c] = d * rs * (which ? gk[c] : gq[c]) + (which ? bk[c] : bq[c]);
    __syncthreads();

    const float* W = (which ? Wk : Wq) + (size_t)c * DIM;
    float acc = 0.f;
#pragma unroll 4
    for (int i = 0; i < DIM; i += 4) {
        float4 wv = *(const float4*)(W + i);      // 16B aligned
        acc = fmaf(ln[i + 0], wv.x, acc);
        acc = fmaf(ln[i + 1], wv.y, acc);
        acc = fmaf(ln[i + 2], wv.z, acc);
        acc = fmaf(ln[i + 3], wv.w, acc);
    }
    (which ? g_kbuf : g_qbuf)[(size_t)(b * NSAMP + s) * DIM + c] = acc;
}

// ============================================================================
// Kernel C2: attention per batch: logits (64x64) -> softmax -> @v -> out1.
// v is the [B,3,S]->[B,S,3] memory reinterpretation of diff_coor.
// ============================================================================
__global__ __launch_bounds__(1024) void attn_kernel(
    float* __restrict__ out1)
{
    const int b = blockIdx.x;
    const int tid = threadIdx.x;
    __shared__ float att[64][64];
    __shared__ float vv[64][3];

    // logits: thread computes row i, cols j0..j0+3
    {
        const int i  = tid >> 4;
        const int j0 = (tid & 15) << 2;
        const float* qr = g_qbuf + (size_t)(b * NSAMP + i) * DIM;
        const float* k0 = g_kbuf + (size_t)(b * NSAMP + j0) * DIM;
        float a0 = 0, a1 = 0, a2 = 0, a3 = 0;
        for (int ii = 0; ii < DIM; ii += 4) {
            float4 qv = *(const float4*)(qr + ii);
            float4 v0 = *(const float4*)(k0 + ii);
            float4 v1 = *(const float4*)(k0 + DIM + ii);
            float4 v2 = *(const float4*)(k0 + 2 * DIM + ii);
            float4 v3 = *(const float4*)(k0 + 3 * DIM + ii);
            a0 += qv.x * v0.x + qv.y * v0.y + qv.z * v0.z + qv.w * v0.w;
            a1 += qv.x * v1.x + qv.y * v1.y + qv.z * v1.z + qv.w * v1.w;
            a2 += qv.x * v2.x + qv.y * v2.y + qv.z * v2.z + qv.w * v2.w;
            a3 += qv.x * v3.x + qv.y * v3.y + qv.z * v3.z + qv.w * v3.w;
        }
        att[i][j0 + 0] = a0 * 0.0625f;   // scale = 1/sqrt(256)
        att[i][j0 + 1] = a1 * 0.0625f;
        att[i][j0 + 2] = a2 * 0.0625f;
        att[i][j0 + 3] = a3 * 0.0625f;
    }
    __syncthreads();

    const int wv_ = tid >> 6, lane = tid & 63;
    // softmax rows (wave per row, 4 rows/wave)
    for (int r = wv_; r < 64; r += 16) {
        float v = att[r][lane];
        float m = v;
#pragma unroll
        for (int off = 32; off; off >>= 1) m = fmaxf(m, __shfl_xor(m, off));
        float e = expf(v - m);
        float ss = e;
#pragma unroll
        for (int off = 32; off; off >>= 1) ss += __shfl_xor(ss, off);
        att[r][lane] = e / ss;
    }
    // build v: flat t = m*3+d reads diff_coor[b, t%64, t/64]
    if (tid < 192) {
        int m = tid / 3, d = tid - 3 * m;
        vv[m][d] = g_diff_coor[(size_t)(b * NSAMP + (tid & 63)) * 3 + (tid >> 6)];
    }
    __syncthreads();

    // coor_2 = attn @ v ; out1 = sample_coor + coor_2  (f32 out)
    for (int r = wv_; r < 64; r += 16) {
        float a = att[r][lane];
        float s0 = a * vv[lane][0];
        float s1 = a * vv[lane][1];
        float s2 = a * vv[lane][2];
#pragma unroll
        for (int off = 32; off; off >>= 1) {
            s0 += __shfl_xor(s0, off);
            s1 += __shfl_xor(s1, off);
            s2 += __shfl_xor(s2, off);
        }
        if (lane == 0) {
            int o = (b * NSAMP + r) * 3;
            out1[o + 0] = g_sample_coor[o + 0] + s0;
            out1[o + 1] = g_sample_coor[o + 1] + s1;
            out1[o + 2] = g_sample_coor[o + 2] + s2;
        }
    }
}

// ============================================================================
extern "C" void kernel_launch(void* const* d_in, const int* in_sizes, int n_in,
                              void* d_out, int out_size, void* d_ws, size_t ws_size,
                              hipStream_t stream)
{
    const float* x    = (const float*)d_in[0];
    const float* coor = (const float*)d_in[1];
    if (in_sizes[0] == BATCH * NPTS * 3) {   // defensive size-based resolution
        x    = (const float*)d_in[1];
        coor = (const float*)d_in[0];
    }
    const float* Wq   = (const float*)d_in[2];
    const float* Wk   = (const float*)d_in[3];
    const float* gq   = (const float*)d_in[4];
    const float* bq   = (const float*)d_in[5];
    const float* gk   = (const float*)d_in[6];
    const float* bk   = (const float*)d_in[7];

    float* out0 = (float*)d_out;                          // [B,S,C] f32
    float* out1 = out0 + (size_t)BATCH * NSAMP * DIM;     // [B,S,3] f32

    hipLaunchKernelGGL(fps_kernel, dim3(BATCH * FPS_BPB), dim3(FPS_TPB), 0, stream,
                       coor);
    hipLaunchKernelGGL(ballquery_kernel, dim3(BATCH * NSAMP), dim3(64), 0, stream,
                       coor, x, out0);
    hipLaunchKernelGGL(ln_gemm_kernel, dim3(BATCH * NSAMP * 2), dim3(256), 0, stream,
                       x, out0, Wq, Wk, gq, bq, gk, bk);
    hipLaunchKernelGGL(attn_kernel, dim3(BATCH), dim3(1024), 0, stream, out1);
}

// Round 2
// 1147.206 us; speedup vs baseline: 2.3787x; 2.3787x over previous
//
#include <hip/hip_runtime.h>

// Problem constants (match reference)
#define BATCH 8
#define NPTS  32768
#define DIM   256
#define NSAMP 64      // NPOINT (fps samples)
#define NNBR  8       // ball-query neighbors
#define LN_EPS 1e-5f

// FPS working-set split (32 slices of 1024 points each):
//   slices [0, K_LDS)                  -> LDS   (60 KB, loaded once)
//   slices [K_LDS, K_LDS+K_REG)        -> VGPRs (60 regs, loaded once)
//   slices [K_LDS+K_REG, 32)           -> streamed from L2 each iteration
#define K_LDS    5
#define K_REG    20
#define K_STREAM 7

// Inter-kernel buffers as device globals (no d_ws dependence).
__device__ float g_sample_coor[BATCH * NSAMP * 3];
__device__ float g_diff_coor[BATCH * NSAMP * 3];
__device__ float g_qbuf[BATCH * NSAMP * DIM];
__device__ float g_kbuf[BATCH * NSAMP * DIM];
__device__ int   g_fidx[BATCH * NSAMP];

// I/O dtypes (forensically established):
//  - inputs  = FLOAT32 storage (R2: reading as bf16 created sNaN patterns -> NaN)
//  - outputs = FLOAT32 storage (R3-R5: bf16 ushort writes gave deterministic
//    6.72 error == interleaved-bf16-read-as-f32 signature)
// FPS distance precision: f32 (matches the reference, which computes d and the
// running min in f32; index logic previously proven robust under f32 variants).
// Ball-query keeps f64 distances (radius threshold compare, unchanged).

__device__ __forceinline__ double dist2_64(float px, float py, float pz,
                                           float cx, float cy, float cz) {
    double dx = (double)px - (double)cx;
    double dy = (double)py - (double)cy;
    double dz = (double)pz - (double)cz;
    return (dx * dx + dy * dy) + dz * dz;   // numpy's (x^2+y^2)+z^2 order
}

// ============================================================================
// Kernel A: farthest-point sampling. One block per batch (NO inter-block
// barrier: R1 showed cross-XCD barriers cost ~37us/iter). 1024 threads,
// 32 points/thread. Coords resident in LDS+registers; dist[] in f32 regs.
// Argmax tie-break: lowest index (strict >, ascending-p processing order).
// ============================================================================
__global__ __launch_bounds__(1024) void fps_kernel(
    const float* __restrict__ coor)
{
    const int b = blockIdx.x;
    const int t = threadIdx.x;
    const float* cb = coor + (size_t)b * NPTS * 3;

    __shared__ float s_coor[K_LDS][1024][3];   // 60 KB
    __shared__ float s_rv[16];
    __shared__ int   s_ri[16];
    __shared__ float s_ctr[3];

    // one-time staging: LDS slices
#pragma unroll
    for (int k = 0; k < K_LDS; ++k) {
        const int p = (k << 10) + t;
        s_coor[k][t][0] = cb[p * 3 + 0];
        s_coor[k][t][1] = cb[p * 3 + 1];
        s_coor[k][t][2] = cb[p * 3 + 2];
    }
    // one-time staging: register slices
    float px[K_REG], py[K_REG], pz[K_REG];
#pragma unroll
    for (int k = 0; k < K_REG; ++k) {
        const int p = ((K_LDS + k) << 10) + t;
        px[k] = cb[p * 3 + 0];
        py[k] = cb[p * 3 + 1];
        pz[k] = cb[p * 3 + 2];
    }

    float dist[32];
#pragma unroll
    for (int k = 0; k < 32; ++k) dist[k] = 1e10f;

    float cx = cb[0], cy = cb[1], cz = cb[2];
    int cidx = 0;                       // only meaningful on t==0
    __syncthreads();

    for (int s = 0; s < NSAMP; ++s) {
        if (t == 0) {
            g_fidx[b * NSAMP + s] = cidx;
            g_sample_coor[(b * NSAMP + s) * 3 + 0] = cx;
            g_sample_coor[(b * NSAMP + s) * 3 + 1] = cy;
            g_sample_coor[(b * NSAMP + s) * 3 + 2] = cz;
        }
        if (s == NSAMP - 1) break;

        float best = -1.0f; int bidx = 0;

        // ---- LDS slices (p ascending) ----
#pragma unroll
        for (int k = 0; k < K_LDS; ++k) {
            float dx = s_coor[k][t][0] - cx;
            float dy = s_coor[k][t][1] - cy;
            float dz = s_coor[k][t][2] - cz;
            float d2 = dx * dx + dy * dy + dz * dz;
            float nd = fminf(dist[k], d2);
            dist[k] = nd;
            if (nd > best) { best = nd; bidx = (k << 10) + t; }
        }
        // ---- register slices ----
#pragma unroll
        for (int k = 0; k < K_REG; ++k) {
            float dx = px[k] - cx;
            float dy = py[k] - cy;
            float dz = pz[k] - cz;
            float d2 = dx * dx + dy * dy + dz * dz;
            float nd = fminf(dist[K_LDS + k], d2);
            dist[K_LDS + k] = nd;
            if (nd > best) { best = nd; bidx = ((K_LDS + k) << 10) + t; }
        }
        // ---- streamed slices (L2-resident after iter 0) ----
#pragma unroll 2
        for (int k = 0; k < K_STREAM; ++k) {
            const int p = ((K_LDS + K_REG + k) << 10) + t;
            float sx = cb[p * 3 + 0];
            float sy = cb[p * 3 + 1];
            float sz = cb[p * 3 + 2];
            float dx = sx - cx, dy = sy - cy, dz = sz - cz;
            float d2 = dx * dx + dy * dy + dz * dz;
            float nd = fminf(dist[K_LDS + K_REG + k], d2);
            dist[K_LDS + K_REG + k] = nd;
            if (nd > best) { best = nd; bidx = p; }
        }

        // ---- wave butterfly argmax, lowest-index tie-break (f32) ----
#pragma unroll
        for (int off = 32; off > 0; off >>= 1) {
            float ov = __shfl_xor(best, off);
            int   oi = __shfl_xor(bidx, off);
            if (ov > best || (ov == best && oi < bidx)) { best = ov; bidx = oi; }
        }
        if ((t & 63) == 0) { s_rv[t >> 6] = best; s_ri[t >> 6] = bidx; }
        __syncthreads();
        if (t == 0) {
            float bv = s_rv[0]; int bi = s_ri[0];
#pragma unroll
            for (int w = 1; w < 16; ++w) {
                float v = s_rv[w]; int i = s_ri[w];
                if (v > bv || (v == bv && i < bi)) { bv = v; bi = i; }
            }
            cidx = bi;
            s_ctr[0] = cb[bi * 3 + 0];
            s_ctr[1] = cb[bi * 3 + 1];
            s_ctr[2] = cb[bi * 3 + 2];
        }
        __syncthreads();
        cx = s_ctr[0]; cy = s_ctr[1]; cz = s_ctr[2];
    }
}

// ============================================================================
// Kernel B: ball query (first-8 within radius by index order, f64 distance,
// early exit) + grouped-feature max (out0 = global_x, f32) + diff_coor mean.
// One wave per (b,s) center.
// ============================================================================
__global__ __launch_bounds__(64) void ballquery_kernel(
    const float* __restrict__ coor,
    const float* __restrict__ x,
    float* __restrict__ out0)
{
    const int bid = blockIdx.x;
    const int b = bid >> 6, s = bid & 63;
    const int lane = threadIdx.x;
    const float* cb = coor + (size_t)b * NPTS * 3;

    const float cx = g_sample_coor[(b * NSAMP + s) * 3 + 0];
    const float cy = g_sample_coor[(b * NSAMP + s) * 3 + 1];
    const float cz = g_sample_coor[(b * NSAMP + s) * 3 + 2];

    __shared__ int s_nidx[NNBR];
    int found = 0;
    for (int ch = 0; ch < NPTS / 64 && found < NNBR; ++ch) {
        int p = (ch << 6) + lane;
        double d2 = dist2_64(cb[p * 3 + 0], cb[p * 3 + 1], cb[p * 3 + 2],
                             cx, cy, cz);
        unsigned long long m = __ballot(d2 < 16.0);   // strict <
        while (m && found < NNBR) {                   // wave-uniform
            int bpos = __ffsll(m) - 1;
            if (lane == 0) s_nidx[found] = (ch << 6) + bpos;
            ++found;
            m &= m - 1;
        }
    }
    if (lane == 0) {                         // pad with first hit (or 0 if none)
        if (found == 0) { s_nidx[0] = 0; found = 1; }
        int f0 = s_nidx[0];
        for (int j = found; j < NNBR; ++j) s_nidx[j] = f0;
    }
    __syncthreads();

    // grouped-feature max -> out0 (4 channels/lane; f32 in, f32 out)
    int c0 = lane * 4;
    float a0 = -1e30f, a1 = -1e30f, a2 = -1e30f, a3 = -1e30f;
#pragma unroll
    for (int j = 0; j < NNBR; ++j) {
        const float4 v = *(const float4*)(x + ((size_t)b * NPTS + s_nidx[j]) * DIM + c0);
        a0 = fmaxf(a0, v.x); a1 = fmaxf(a1, v.y);
        a2 = fmaxf(a2, v.z); a3 = fmaxf(a3, v.w);
    }
    float4 o; o.x = a0; o.y = a1; o.z = a2; o.w = a3;
    *(float4*)(out0 + ((size_t)(b * NSAMP + s)) * DIM + c0) = o;

    // diff_coor = mean_j (p_j - c)   (continuous path)
    if (lane < 3) {
        float sum = 0.f;
#pragma unroll
        for (int j = 0; j < NNBR; ++j) {
            float pv = cb[s_nidx[j] * 3 + lane];
            sum += pv - ((lane == 0) ? cx : (lane == 1) ? cy : cz);
        }
        g_diff_coor[(b * NSAMP + s) * 3 + lane] = sum * 0.125f;
    }
}

// ============================================================================
// Kernel C1: LayerNorm + row @ W^T. One block per (b, s, which) row.
// which==0: q from diff_x = global_x(out0) - sample_x ; which==1: k from sample_x.
// ============================================================================
__global__ __launch_bounds__(256) void ln_gemm_kernel(
    const float* __restrict__ x,
    const float* __restrict__ out0,
    const float* __restrict__ Wq,
    const float* __restrict__ Wk,
    const float* __restrict__ gq, const float* __restrict__ bq,
    const float* __restrict__ gk, const float* __restrict__ bk)
{
    const int bid = blockIdx.x;
    const int which = bid & 1;
    const int s = (bid >> 1) & 63;
    const int b = bid >> 7;
    const int c = threadIdx.x;

    const int fidx = g_fidx[b * NSAMP + s];
    float xs = x[((size_t)b * NPTS + fidx) * DIM + c];
    float r  = which ? xs : (out0[(size_t)(b * NSAMP + s) * DIM + c] - xs);

    __shared__ float red[4];
    __shared__ float ln[DIM];

    float sum = r;
#pragma unroll
    for (int off = 32; off; off >>= 1) sum += __shfl_xor(sum, off);
    int wid = c >> 6;
    if ((c & 63) == 0) red[wid] = sum;
    __syncthreads();
    float mean = (red[0] + red[1] + red[2] + red[3]) * (1.0f / DIM);
    float d = r - mean;
    float vs = d * d;
#pragma unroll
    for (int off = 32; off; off >>= 1) vs += __shfl_xor(vs, off);
    __syncthreads();
    if ((c & 63) == 0) red[wid] = vs;
    __syncthreads();
    float var = (red[0] + red[1] + red[2] + red[3]) * (1.0f / DIM);
    float rs = 1.0f / sqrtf(var + LN_EPS);

    ln[c] = d * rs * (which ? gk[c] : gq[c]) + (which ? bk[c] : bq[c]);
    __syncthreads();

    const float* W = (which ? Wk : Wq) + (size_t)c * DIM;
    float acc = 0.f;
#pragma unroll 4
    for (int i = 0; i < DIM; i += 4) {
        float4 wv = *(const float4*)(W + i);      // 16B aligned
        acc = fmaf(ln[i + 0], wv.x, acc);
        acc = fmaf(ln[i + 1], wv.y, acc);
        acc = fmaf(ln[i + 2], wv.z, acc);
        acc = fmaf(ln[i + 3], wv.w, acc);
    }
    (which ? g_kbuf : g_qbuf)[(size_t)(b * NSAMP + s) * DIM + c] = acc;
}

// ============================================================================
// Kernel C2: attention per batch: logits (64x64) -> softmax -> @v -> out1.
// v is the [B,3,S]->[B,S,3] memory reinterpretation of diff_coor.
// ============================================================================
__global__ __launch_bounds__(1024) void attn_kernel(
    float* __restrict__ out1)
{
    const int b = blockIdx.x;
    const int tid = threadIdx.x;
    __shared__ float att[64][64];
    __shared__ float vv[64][3];

    // logits: thread computes row i, cols j0..j0+3
    {
        const int i  = tid >> 4;
        const int j0 = (tid & 15) << 2;
        const float* qr = g_qbuf + (size_t)(b * NSAMP + i) * DIM;
        const float* k0 = g_kbuf + (size_t)(b * NSAMP + j0) * DIM;
        float a0 = 0, a1 = 0, a2 = 0, a3 = 0;
        for (int ii = 0; ii < DIM; ii += 4) {
            float4 qv = *(const float4*)(qr + ii);
            float4 v0 = *(const float4*)(k0 + ii);
            float4 v1 = *(const float4*)(k0 + DIM + ii);
            float4 v2 = *(const float4*)(k0 + 2 * DIM + ii);
            float4 v3 = *(const float4*)(k0 + 3 * DIM + ii);
            a0 += qv.x * v0.x + qv.y * v0.y + qv.z * v0.z + qv.w * v0.w;
            a1 += qv.x * v1.x + qv.y * v1.y + qv.z * v1.z + qv.w * v1.w;
            a2 += qv.x * v2.x + qv.y * v2.y + qv.z * v2.z + qv.w * v2.w;
            a3 += qv.x * v3.x + qv.y * v3.y + qv.z * v3.z + qv.w * v3.w;
        }
        att[i][j0 + 0] = a0 * 0.0625f;   // scale = 1/sqrt(256)
        att[i][j0 + 1] = a1 * 0.0625f;
        att[i][j0 + 2] = a2 * 0.0625f;
        att[i][j0 + 3] = a3 * 0.0625f;
    }
    __syncthreads();

    const int wv_ = tid >> 6, lane = tid & 63;
    // softmax rows (wave per row, 4 rows/wave)
    for (int r = wv_; r < 64; r += 16) {
        float v = att[r][lane];
        float m = v;
#pragma unroll
        for (int off = 32; off; off >>= 1) m = fmaxf(m, __shfl_xor(m, off));
        float e = expf(v - m);
        float ss = e;
#pragma unroll
        for (int off = 32; off; off >>= 1) ss += __shfl_xor(ss, off);
        att[r][lane] = e / ss;
    }
    // build v: flat t = m*3+d reads diff_coor[b, t%64, t/64]
    if (tid < 192) {
        int m = tid / 3, d = tid - 3 * m;
        vv[m][d] = g_diff_coor[(size_t)(b * NSAMP + (tid & 63)) * 3 + (tid >> 6)];
    }
    __syncthreads();

    // coor_2 = attn @ v ; out1 = sample_coor + coor_2  (f32 out)
    for (int r = wv_; r < 64; r += 16) {
        float a = att[r][lane];
        float s0 = a * vv[lane][0];
        float s1 = a * vv[lane][1];
        float s2 = a * vv[lane][2];
#pragma unroll
        for (int off = 32; off; off >>= 1) {
            s0 += __shfl_xor(s0, off);
            s1 += __shfl_xor(s1, off);
            s2 += __shfl_xor(s2, off);
        }
        if (lane == 0) {
            int o = (b * NSAMP + r) * 3;
            out1[o + 0] = g_sample_coor[o + 0] + s0;
            out1[o + 1] = g_sample_coor[o + 1] + s1;
            out1[o + 2] = g_sample_coor[o + 2] + s2;
        }
    }
}

// ============================================================================
extern "C" void kernel_launch(void* const* d_in, const int* in_sizes, int n_in,
                              void* d_out, int out_size, void* d_ws, size_t ws_size,
                              hipStream_t stream)
{
    const float* x    = (const float*)d_in[0];
    const float* coor = (const float*)d_in[1];
    if (in_sizes[0] == BATCH * NPTS * 3) {   // defensive size-based resolution
        x    = (const float*)d_in[1];
        coor = (const float*)d_in[0];
    }
    const float* Wq   = (const float*)d_in[2];
    const float* Wk   = (const float*)d_in[3];
    const float* gq   = (const float*)d_in[4];
    const float* bq   = (const float*)d_in[5];
    const float* gk   = (const float*)d_in[6];
    const float* bk   = (const float*)d_in[7];

    float* out0 = (float*)d_out;                          // [B,S,C] f32
    float* out1 = out0 + (size_t)BATCH * NSAMP * DIM;     // [B,S,3] f32

    hipLaunchKernelGGL(fps_kernel, dim3(BATCH), dim3(1024), 0, stream, coor);
    hipLaunchKernelGGL(ballquery_kernel, dim3(BATCH * NSAMP), dim3(64), 0, stream,
                       coor, x, out0);
    hipLaunchKernelGGL(ln_gemm_kernel, dim3(BATCH * NSAMP * 2), dim3(256), 0, stream,
                       x, out0, Wq, Wk, gq, bq, gk, bk);
    hipLaunchKernelGGL(attn_kernel, dim3(BATCH), dim3(1024), 0, stream, out1);
}

// Round 3
// 748.616 us; speedup vs baseline: 3.6451x; 1.5324x over previous
//
#include <hip/hip_runtime.h>

// Problem constants (match reference)
#define BATCH 8
#define NPTS  32768
#define DIM   256
#define NSAMP 64      // NPOINT (fps samples)
#define NNBR  8       // ball-query neighbors
#define LN_EPS 1e-5f

// FPS working-set split (32 slices of 1024 points each):
//   slices [0, K_LDS)                  -> LDS   (144 KB, loaded once)
//   slices [K_LDS, K_LDS+K_REG)        -> VGPRs (36 regs, loaded once)
//   slices [K_LDS+K_REG, 32)           -> streamed from L2 each iteration
// R2 lesson: with __launch_bounds__(1024) the compiler capped VGPRs at 64 and
// spilled ~30 regs/thread to scratch (VGPR_Count=64 in rocprof) -> 11us/iter.
// Fix: __launch_bounds__(1024,4) = 1 block/CU = 128 VGPR budget, and keep the
// live register set ~90.
#define K_LDS    12
#define K_REG    12
#define K_STREAM 8

// Inter-kernel buffers as device globals (no d_ws dependence).
__device__ float g_sample_coor[BATCH * NSAMP * 3];
__device__ float g_diff_coor[BATCH * NSAMP * 3];
__device__ float g_qbuf[BATCH * NSAMP * DIM];
__device__ float g_kbuf[BATCH * NSAMP * DIM];
__device__ int   g_fidx[BATCH * NSAMP];

// I/O dtypes (forensically established):
//  - inputs  = FLOAT32 storage (R2: reading as bf16 created sNaN patterns -> NaN)
//  - outputs = FLOAT32 storage (R3-R5: bf16 ushort writes gave deterministic
//    6.72 error == interleaved-bf16-read-as-f32 signature)
// FPS distance precision: f32 (matches the reference; verified passing in R2).
// Ball-query keeps f64 distances (radius threshold compare, unchanged).

__device__ __forceinline__ double dist2_64(float px, float py, float pz,
                                           float cx, float cy, float cz) {
    double dx = (double)px - (double)cx;
    double dy = (double)py - (double)cy;
    double dz = (double)pz - (double)cz;
    return (dx * dx + dy * dy) + dz * dz;   // numpy's (x^2+y^2)+z^2 order
}

// ============================================================================
// Kernel A: farthest-point sampling. One block per batch (NO inter-block
// barrier: R1 showed cross-XCD barriers cost ~37us/iter). 1024 threads,
// 32 points/thread. Coords resident in LDS+registers; dist[] in f32 regs.
// Argmax tie-break: lowest index (strict >, ascending-p processing order).
// ============================================================================
__global__ __launch_bounds__(1024, 4) void fps_kernel(
    const float* __restrict__ coor)
{
    const int b = blockIdx.x;
    const int t = threadIdx.x;
    const float* cb = coor + (size_t)b * NPTS * 3;

    __shared__ float s_coor[K_LDS][1024][3];   // 144 KB (gfx950: 160 KB/WG max)
    __shared__ float s_rv[16];
    __shared__ int   s_ri[16];
    __shared__ float s_ctr[3];

    // one-time staging: LDS slices
#pragma unroll
    for (int k = 0; k < K_LDS; ++k) {
        const int p = (k << 10) + t;
        s_coor[k][t][0] = cb[p * 3 + 0];
        s_coor[k][t][1] = cb[p * 3 + 1];
        s_coor[k][t][2] = cb[p * 3 + 2];
    }
    // one-time staging: register slices
    float px[K_REG], py[K_REG], pz[K_REG];
#pragma unroll
    for (int k = 0; k < K_REG; ++k) {
        const int p = ((K_LDS + k) << 10) + t;
        px[k] = cb[p * 3 + 0];
        py[k] = cb[p * 3 + 1];
        pz[k] = cb[p * 3 + 2];
    }

    float dist[32];
#pragma unroll
    for (int k = 0; k < 32; ++k) dist[k] = 1e10f;

    float cx = cb[0], cy = cb[1], cz = cb[2];
    int cidx = 0;                       // only meaningful on t==0
    __syncthreads();

    for (int s = 0; s < NSAMP; ++s) {
        if (t == 0) {
            g_fidx[b * NSAMP + s] = cidx;
            g_sample_coor[(b * NSAMP + s) * 3 + 0] = cx;
            g_sample_coor[(b * NSAMP + s) * 3 + 1] = cy;
            g_sample_coor[(b * NSAMP + s) * 3 + 2] = cz;
        }
        if (s == NSAMP - 1) break;

        float best = -1.0f; int bidx = 0;

        // ---- LDS slices (p ascending) ----
#pragma unroll
        for (int k = 0; k < K_LDS; ++k) {
            float dx = s_coor[k][t][0] - cx;
            float dy = s_coor[k][t][1] - cy;
            float dz = s_coor[k][t][2] - cz;
            float d2 = dx * dx + dy * dy + dz * dz;
            float nd = fminf(dist[k], d2);
            dist[k] = nd;
            if (nd > best) { best = nd; bidx = (k << 10) + t; }
        }
        // ---- register slices ----
#pragma unroll
        for (int k = 0; k < K_REG; ++k) {
            float dx = px[k] - cx;
            float dy = py[k] - cy;
            float dz = pz[k] - cz;
            float d2 = dx * dx + dy * dy + dz * dz;
            float nd = fminf(dist[K_LDS + k], d2);
            dist[K_LDS + k] = nd;
            if (nd > best) { best = nd; bidx = ((K_LDS + k) << 10) + t; }
        }
        // ---- streamed slices (L2-resident after iter 0) ----
#pragma unroll 2
        for (int k = 0; k < K_STREAM; ++k) {
            const int p = ((K_LDS + K_REG + k) << 10) + t;
            float sx = cb[p * 3 + 0];
            float sy = cb[p * 3 + 1];
            float sz = cb[p * 3 + 2];
            float dx = sx - cx, dy = sy - cy, dz = sz - cz;
            float d2 = dx * dx + dy * dy + dz * dz;
            float nd = fminf(dist[K_LDS + K_REG + k], d2);
            dist[K_LDS + K_REG + k] = nd;
            if (nd > best) { best = nd; bidx = p; }
        }

        // ---- wave butterfly argmax, lowest-index tie-break (f32) ----
#pragma unroll
        for (int off = 32; off > 0; off >>= 1) {
            float ov = __shfl_xor(best, off);
            int   oi = __shfl_xor(bidx, off);
            if (ov > best || (ov == best && oi < bidx)) { best = ov; bidx = oi; }
        }
        if ((t & 63) == 0) { s_rv[t >> 6] = best; s_ri[t >> 6] = bidx; }
        __syncthreads();

        // ---- wave-0 16-lane butterfly over the per-wave partials ----
        if (t < 64) {
            float bv = (t < 16) ? s_rv[t] : -2.0f;     // real dists >= 0
            int   bi = (t < 16) ? s_ri[t] : 0x7fffffff;
#pragma unroll
            for (int off = 8; off > 0; off >>= 1) {
                float ov = __shfl_xor(bv, off);
                int   oi = __shfl_xor(bi, off);
                if (ov > bv || (ov == bv && oi < bi)) { bv = ov; bi = oi; }
            }
            if (t == 0) {
                cidx = bi;
                s_ctr[0] = cb[bi * 3 + 0];
                s_ctr[1] = cb[bi * 3 + 1];
                s_ctr[2] = cb[bi * 3 + 2];
            }
        }
        __syncthreads();
        cx = s_ctr[0]; cy = s_ctr[1]; cz = s_ctr[2];
    }
}

// ============================================================================
// Kernel B: ball query (first-8 within radius by index order, f64 distance,
// early exit) + grouped-feature max (out0 = global_x, f32) + diff_coor mean.
// One wave per (b,s) center.
// ============================================================================
__global__ __launch_bounds__(64) void ballquery_kernel(
    const float* __restrict__ coor,
    const float* __restrict__ x,
    float* __restrict__ out0)
{
    const int bid = blockIdx.x;
    const int b = bid >> 6, s = bid & 63;
    const int lane = threadIdx.x;
    const float* cb = coor + (size_t)b * NPTS * 3;

    const float cx = g_sample_coor[(b * NSAMP + s) * 3 + 0];
    const float cy = g_sample_coor[(b * NSAMP + s) * 3 + 1];
    const float cz = g_sample_coor[(b * NSAMP + s) * 3 + 2];

    __shared__ int s_nidx[NNBR];
    int found = 0;
    for (int ch = 0; ch < NPTS / 64 && found < NNBR; ++ch) {
        int p = (ch << 6) + lane;
        double d2 = dist2_64(cb[p * 3 + 0], cb[p * 3 + 1], cb[p * 3 + 2],
                             cx, cy, cz);
        unsigned long long m = __ballot(d2 < 16.0);   // strict <
        while (m && found < NNBR) {                   // wave-uniform
            int bpos = __ffsll(m) - 1;
            if (lane == 0) s_nidx[found] = (ch << 6) + bpos;
            ++found;
            m &= m - 1;
        }
    }
    if (lane == 0) {                         // pad with first hit (or 0 if none)
        if (found == 0) { s_nidx[0] = 0; found = 1; }
        int f0 = s_nidx[0];
        for (int j = found; j < NNBR; ++j) s_nidx[j] = f0;
    }
    __syncthreads();

    // grouped-feature max -> out0 (4 channels/lane; f32 in, f32 out)
    int c0 = lane * 4;
    float a0 = -1e30f, a1 = -1e30f, a2 = -1e30f, a3 = -1e30f;
#pragma unroll
    for (int j = 0; j < NNBR; ++j) {
        const float4 v = *(const float4*)(x + ((size_t)b * NPTS + s_nidx[j]) * DIM + c0);
        a0 = fmaxf(a0, v.x); a1 = fmaxf(a1, v.y);
        a2 = fmaxf(a2, v.z); a3 = fmaxf(a3, v.w);
    }
    float4 o; o.x = a0; o.y = a1; o.z = a2; o.w = a3;
    *(float4*)(out0 + ((size_t)(b * NSAMP + s)) * DIM + c0) = o;

    // diff_coor = mean_j (p_j - c)   (continuous path)
    if (lane < 3) {
        float sum = 0.f;
#pragma unroll
        for (int j = 0; j < NNBR; ++j) {
            float pv = cb[s_nidx[j] * 3 + lane];
            sum += pv - ((lane == 0) ? cx : (lane == 1) ? cy : cz);
        }
        g_diff_coor[(b * NSAMP + s) * 3 + lane] = sum * 0.125f;
    }
}

// ============================================================================
// Kernel C1: LayerNorm + row @ W^T. One block per (b, s, which) row.
// which==0: q from diff_x = global_x(out0) - sample_x ; which==1: k from sample_x.
// ============================================================================
__global__ __launch_bounds__(256) void ln_gemm_kernel(
    const float* __restrict__ x,
    const float* __restrict__ out0,
    const float* __restrict__ Wq,
    const float* __restrict__ Wk,
    const float* __restrict__ gq, const float* __restrict__ bq,
    const float* __restrict__ gk, const float* __restrict__ bk)
{
    const int bid = blockIdx.x;
    const int which = bid & 1;
    const int s = (bid >> 1) & 63;
    const int b = bid >> 7;
    const int c = threadIdx.x;

    const int fidx = g_fidx[b * NSAMP + s];
    float xs = x[((size_t)b * NPTS + fidx) * DIM + c];
    float r  = which ? xs : (out0[(size_t)(b * NSAMP + s) * DIM + c] - xs);

    __shared__ float red[4];
    __shared__ float ln[DIM];

    float sum = r;
#pragma unroll
    for (int off = 32; off; off >>= 1) sum += __shfl_xor(sum, off);
    int wid = c >> 6;
    if ((c & 63) == 0) red[wid] = sum;
    __syncthreads();
    float mean = (red[0] + red[1] + red[2] + red[3]) * (1.0f / DIM);
    float d = r - mean;
    float vs = d * d;
#pragma unroll
    for (int off = 32; off; off >>= 1) vs += __shfl_xor(vs, off);
    __syncthreads();
    if ((c & 63) == 0) red[wid] = vs;
    __syncthreads();
    float var = (red[0] + red[1] + red[2] + red[3]) * (1.0f / DIM);
    float rs = 1.0f / sqrtf(var + LN_EPS);

    ln[c] = d * rs * (which ? gk[c] : gq[c]) + (which ? bk[c] : bq[c]);
    __syncthreads();

    const float* W = (which ? Wk : Wq) + (size_t)c * DIM;
    float acc = 0.f;
#pragma unroll 4
    for (int i = 0; i < DIM; i += 4) {
        float4 wv = *(const float4*)(W + i);      // 16B aligned
        acc = fmaf(ln[i + 0], wv.x, acc);
        acc = fmaf(ln[i + 1], wv.y, acc);
        acc = fmaf(ln[i + 2], wv.z, acc);
        acc = fmaf(ln[i + 3], wv.w, acc);
    }
    (which ? g_kbuf : g_qbuf)[(size_t)(b * NSAMP + s) * DIM + c] = acc;
}

// ============================================================================
// Kernel C2: attention per batch: logits (64x64) -> softmax -> @v -> out1.
// v is the [B,3,S]->[B,S,3] memory reinterpretation of diff_coor.
// ============================================================================
__global__ __launch_bounds__(1024) void attn_kernel(
    float* __restrict__ out1)
{
    const int b = blockIdx.x;
    const int tid = threadIdx.x;
    __shared__ float att[64][64];
    __shared__ float vv[64][3];

    // logits: thread computes row i, cols j0..j0+3
    {
        const int i  = tid >> 4;
        const int j0 = (tid & 15) << 2;
        const float* qr = g_qbuf + (size_t)(b * NSAMP + i) * DIM;
        const float* k0 = g_kbuf + (size_t)(b * NSAMP + j0) * DIM;
        float a0 = 0, a1 = 0, a2 = 0, a3 = 0;
        for (int ii = 0; ii < DIM; ii += 4) {
            float4 qv = *(const float4*)(qr + ii);
            float4 v0 = *(const float4*)(k0 + ii);
            float4 v1 = *(const float4*)(k0 + DIM + ii);
            float4 v2 = *(const float4*)(k0 + 2 * DIM + ii);
            float4 v3 = *(const float4*)(k0 + 3 * DIM + ii);
            a0 += qv.x * v0.x + qv.y * v0.y + qv.z * v0.z + qv.w * v0.w;
            a1 += qv.x * v1.x + qv.y * v1.y + qv.z * v1.z + qv.w * v1.w;
            a2 += qv.x * v2.x + qv.y * v2.y + qv.z * v2.z + qv.w * v2.w;
            a3 += qv.x * v3.x + qv.y * v3.y + qv.z * v3.z + qv.w * v3.w;
        }
        att[i][j0 + 0] = a0 * 0.0625f;   // scale = 1/sqrt(256)
        att[i][j0 + 1] = a1 * 0.0625f;
        att[i][j0 + 2] = a2 * 0.0625f;
        att[i][j0 + 3] = a3 * 0.0625f;
    }
    __syncthreads();

    const int wv_ = tid >> 6, lane = tid & 63;
    // softmax rows (wave per row, 4 rows/wave)
    for (int r = wv_; r < 64; r += 16) {
        float v = att[r][lane];
        float m = v;
#pragma unroll
        for (int off = 32; off; off >>= 1) m = fmaxf(m, __shfl_xor(m, off));
        float e = expf(v - m);
        float ss = e;
#pragma unroll
        for (int off = 32; off; off >>= 1) ss += __shfl_xor(ss, off);
        att[r][lane] = e / ss;
    }
    // build v: flat t = m*3+d reads diff_coor[b, t%64, t/64]
    if (tid < 192) {
        int m = tid / 3, d = tid - 3 * m;
        vv[m][d] = g_diff_coor[(size_t)(b * NSAMP + (tid & 63)) * 3 + (tid >> 6)];
    }
    __syncthreads();

    // coor_2 = attn @ v ; out1 = sample_coor + coor_2  (f32 out)
    for (int r = wv_; r < 64; r += 16) {
        float a = att[r][lane];
        float s0 = a * vv[lane][0];
        float s1 = a * vv[lane][1];
        float s2 = a * vv[lane][2];
#pragma unroll
        for (int off = 32; off; off >>= 1) {
            s0 += __shfl_xor(s0, off);
            s1 += __shfl_xor(s1, off);
            s2 += __shfl_xor(s2, off);
        }
        if (lane == 0) {
            int o = (b * NSAMP + r) * 3;
            out1[o + 0] = g_sample_coor[o + 0] + s0;
            out1[o + 1] = g_sample_coor[o + 1] + s1;
            out1[o + 2] = g_sample_coor[o + 2] + s2;
        }
    }
}

// ============================================================================
extern "C" void kernel_launch(void* const* d_in, const int* in_sizes, int n_in,
                              void* d_out, int out_size, void* d_ws, size_t ws_size,
                              hipStream_t stream)
{
    const float* x    = (const float*)d_in[0];
    const float* coor = (const float*)d_in[1];
    if (in_sizes[0] == BATCH * NPTS * 3) {   // defensive size-based resolution
        x    = (const float*)d_in[1];
        coor = (const float*)d_in[0];
    }
    const float* Wq   = (const float*)d_in[2];
    const float* Wk   = (const float*)d_in[3];
    const float* gq   = (const float*)d_in[4];
    const float* bq   = (const float*)d_in[5];
    const float* gk   = (const float*)d_in[6];
    const float* bk   = (const float*)d_in[7];

    float* out0 = (float*)d_out;                          // [B,S,C] f32
    float* out1 = out0 + (size_t)BATCH * NSAMP * DIM;     // [B,S,3] f32

    hipLaunchKernelGGL(fps_kernel, dim3(BATCH), dim3(1024), 0, stream, coor);
    hipLaunchKernelGGL(ballquery_kernel, dim3(BATCH * NSAMP), dim3(64), 0, stream,
                       coor, x, out0);
    hipLaunchKernelGGL(ln_gemm_kernel, dim3(BATCH * NSAMP * 2), dim3(256), 0, stream,
                       x, out0, Wq, Wk, gq, bq, gk, bk);
    hipLaunchKernelGGL(attn_kernel, dim3(BATCH), dim3(1024), 0, stream, out1);
}